// Round 1
// baseline (271.714 us; speedup 1.0000x reference)
//
#include <hip/hip_runtime.h>

#define IMG 512
#define HALO 5
#define BAND 16
#define NBANDS 32   // 512 / 16

// Gaussian window, sigma=1.5, ws=11, normalized (matches reference _make_window)
#define W0 1.0283800e-03f
#define W1 7.5987582e-03f
#define W2 3.6000773e-02f
#define W3 1.0936070e-01f
#define W4 2.1300553e-01f
#define W5 2.6601172e-01f

__global__ __launch_bounds__(256, 2)
void ssim_main(const float* __restrict__ img1, const float* __restrict__ img2,
               float* __restrict__ part)
{
    const float W[11] = {W0,W1,W2,W3,W4,W5,W4,W3,W2,W1,W0};
    constexpr float C1 = 1.0e-4f;   // 0.01^2
    constexpr float C2 = 9.0e-4f;   // 0.03^2

    // sIn: input band (up to 21 rows for prologue) x 74 cols used, stride 81 (odd -> 2-way banks)
    __shared__ float sIn[2][21][81];
    // sH: ring buffer of horizontal-blur results, 5 channels x 32 rows x 64 cols, stride 65
    __shared__ float sH[5][32][65];
    __shared__ float sRed[4];

    const int bx  = blockIdx.x;
    const int n   = bx >> 3;            // batch image 0..63
    const int gx0 = (bx & 7) << 6;      // stripe start col
    const int tid = threadIdx.x;

    const float* __restrict__ base1 = img1 + (size_t)n * IMG * IMG;
    const float* __restrict__ base2 = img2 + (size_t)n * IMG * IMG;

    float acc = 0.0f;

    // ---- A: load a band of input rows [rbase, rbase+nrows) into sIn (zero-padded) ----
    auto loadBand = [&](int rbase, int nrows) {
        const int total = nrows * 74;
        for (int e = tid; e < total; e += 256) {
            int i  = e / 74;
            int c  = e - i * 74;          // 0..73
            int gr = rbase + i;           // gr >= 0 by construction
            int gc = gx0 - HALO + c;
            bool ok = (gr < IMG) && (gc >= 0) && (gc < IMG);
            size_t off = (size_t)gr * IMG + gc;
            float v1 = ok ? base1[off] : 0.0f;
            float v2 = ok ? base2[off] : 0.0f;
            sIn[0][i][c] = v1;
            sIn[1][i][c] = v2;
        }
    };

    // ---- B: horizontal blur of sIn row rr (absolute row ar), 4 output cols per call ----
    auto horiz = [&](int rr, int ar, int cg) {
        const int c0 = cg << 2;
        float a[14], b[14], xx[14], yy[14], xy[14];
        #pragma unroll
        for (int j = 0; j < 14; ++j) {
            float x = sIn[0][rr][c0 + j];
            float y = sIn[1][rr][c0 + j];
            a[j] = x; b[j] = y;
            xx[j] = x * x; yy[j] = y * y; xy[j] = x * y;
        }
        const int slot = ar & 31;
        #pragma unroll
        for (int o = 0; o < 4; ++o) {
            float s0=0.f, s1=0.f, s2=0.f, s3=0.f, s4=0.f;
            #pragma unroll
            for (int k = 0; k < 11; ++k) {
                float w = W[k];
                s0 = fmaf(w, a [o+k], s0);
                s1 = fmaf(w, b [o+k], s1);
                s2 = fmaf(w, xx[o+k], s2);
                s3 = fmaf(w, yy[o+k], s3);
                s4 = fmaf(w, xy[o+k], s4);
            }
            sH[0][slot][c0+o] = s0;
            sH[1][slot][c0+o] = s1;
            sH[2][slot][c0+o] = s2;
            sH[3][slot][c0+o] = s3;
            sH[4][slot][c0+o] = s4;
        }
    };

    // ---- C: vertical blur + SSIM for output rows [r0, r0+16), 4 rows/thread sliding ----
    auto vert = [&](int r0) {
        const int wv  = tid >> 6;        // wave id 0..3 -> row group (wave-uniform)
        const int col = tid & 63;
        const int rb  = r0 + (wv << 2) - HALO;   // first H row needed
        float v0[14], v1[14], v2[14], v3[14], v4[14];
        #pragma unroll
        for (int i = 0; i < 14; ++i) {
            int slot = (rb + i) & 31;
            v0[i] = sH[0][slot][col];
            v1[i] = sH[1][slot][col];
            v2[i] = sH[2][slot][col];
            v3[i] = sH[3][slot][col];
            v4[i] = sH[4][slot][col];
        }
        #pragma unroll
        for (int q = 0; q < 4; ++q) {
            float m1=0.f, m2=0.f, e11=0.f, e22=0.f, e12=0.f;
            #pragma unroll
            for (int k = 0; k < 11; ++k) {
                float w = W[k];
                m1  = fmaf(w, v0[q+k], m1);
                m2  = fmaf(w, v1[q+k], m2);
                e11 = fmaf(w, v2[q+k], e11);
                e22 = fmaf(w, v3[q+k], e22);
                e12 = fmaf(w, v4[q+k], e12);
            }
            float mu1s = m1 * m1, mu2s = m2 * m2, mu12 = m1 * m2;
            float g1 = e11 - mu1s, g2 = e22 - mu2s, g12 = e12 - mu12;
            float num = (2.0f * mu12 + C1) * (2.0f * g12 + C2);
            float den = (mu1s + mu2s + C1) * (g1 + g2 + C2);
            acc += num * __builtin_amdgcn_rcpf(den);
        }
    };

    // ---- prologue: zero ring slots for rows -5..-1 (slots 27..31), load+blur rows 0..20 ----
    if (tid < 64) {
        #pragma unroll
        for (int ch = 0; ch < 5; ++ch)
            #pragma unroll
            for (int s = 27; s < 32; ++s)
                sH[ch][s][tid] = 0.0f;
    }
    loadBand(0, 21);
    __syncthreads();
    for (int task = tid; task < 21 * 16; task += 256)
        horiz(task >> 4, task >> 4, task & 15);

    // ---- main band loop: 2 barriers per band; next loads overlap vertical compute ----
    for (int b = 0; b < NBANDS; ++b) {
        const int r0 = b * BAND;
        __syncthreads();                         // H(b) ready; prev sIn readers done
        if (b + 1 < NBANDS)
            loadBand(16 * (b + 1) + HALO, 16);   // issue global loads early (overlap with vert)
        vert(r0);
        __syncthreads();                         // vert reads done (WAR on sH); sIn ready
        if (b + 1 < NBANDS) {
            const int rbase = 16 * (b + 1) + HALO;
            horiz(tid >> 4, rbase + (tid >> 4), tid & 15);
        }
    }

    // ---- block reduction -> one partial per block ----
    #pragma unroll
    for (int off = 32; off > 0; off >>= 1)
        acc += __shfl_down(acc, off, 64);
    if ((tid & 63) == 0) sRed[tid >> 6] = acc;
    __syncthreads();
    if (tid == 0) part[bx] = sRed[0] + sRed[1] + sRed[2] + sRed[3];
}

__global__ void ssim_finalize(const float* __restrict__ part, float* __restrict__ out)
{
    double s = 0.0;
    const int t = threadIdx.x;
    for (int i = t; i < 512; i += 64) s += (double)part[i];
    #pragma unroll
    for (int off = 32; off > 0; off >>= 1)
        s += __shfl_down(s, off, 64);
    if (t == 0) out[0] = (float)(s * (1.0 / 16777216.0));
}

extern "C" void kernel_launch(void* const* d_in, const int* in_sizes, int n_in,
                              void* d_out, int out_size, void* d_ws, size_t ws_size,
                              hipStream_t stream)
{
    const float* img1 = (const float*)d_in[0];
    const float* img2 = (const float*)d_in[1];
    float* out  = (float*)d_out;
    float* part = (float*)d_ws;      // 512 floats of scratch

    ssim_main<<<512, 256, 0, stream>>>(img1, img2, part);
    ssim_finalize<<<1, 64, 0, stream>>>(part, out);
}

// Round 2
// 264.429 us; speedup vs baseline: 1.0276x; 1.0276x over previous
//
#include <hip/hip_runtime.h>

#define IMG 512
#define HALO 5
#define BAND 16
#define NB 16          // bands per block (256 rows / 16)
#define RING 28        // ring slots: >= 26 live rows

// Gaussian window, sigma=1.5, ws=11, normalized (matches reference _make_window)
#define W0 1.0283800e-03f
#define W1 7.5987582e-03f
#define W2 3.6000773e-02f
#define W3 1.0936070e-01f
#define W4 2.1300553e-01f
#define W5 2.6601172e-01f

__global__ __launch_bounds__(256, 4)
void ssim_main(const float* __restrict__ img1, const float* __restrict__ img2,
               float* __restrict__ part)
{
    const float W[11] = {W0,W1,W2,W3,W4,W5,W4,W3,W2,W1,W0};
    constexpr float C1 = 1.0e-4f;
    constexpr float C2 = 9.0e-4f;

    // Ring of horizontal-blur results. 4 channels packed (h-blur of x, y, xx, yy),
    // 5th channel (xy) separate. Strides chosen for <=2-way LDS banking.
    __shared__ float4 sH4[RING][65];   // 29120 B
    __shared__ float  sH1[RING][65];   // 7280 B
    __shared__ float  sRed[4];         // total ~36.4 KB -> 4 blocks/CU

    const int bx   = blockIdx.x;
    const int n    = bx >> 4;                 // image 0..63
    const int gx0  = ((bx >> 1) & 7) << 6;    // stripe start col (64-wide)
    const int half = bx & 1;                  // row half: 0 -> rows 0..255, 1 -> 256..511
    const int base = half << 8;
    const int tid  = threadIdx.x;

    const float* __restrict__ base1 = img1 + (size_t)n * IMG * IMG;
    const float* __restrict__ base2 = img2 + (size_t)n * IMG * IMG;

    float acc = 0.0f;

    // ---- horizontal blur of global row gr -> ring[slot], 4 output cols (cg*4..+3).
    // Rows/cols outside the image contribute zeros (predicated loads).
    auto horiz = [&](int gr, int slot, int cg) {
        const int c0  = cg << 2;        // local col 0..60
        const int gcb = gx0 + c0;       // global col of output c0
        const float* r1 = base1 + (ptrdiff_t)gr * IMG;
        const float* r2 = base2 + (ptrdiff_t)gr * IMG;
        const bool rok = ((unsigned)gr < (unsigned)IMG);
        float xr[20], yr[20];
        #pragma unroll
        for (int t = 0; t < 5; ++t) {
            int gc = gcb - 8 + (t << 2);          // aligned float4, fully in or out
            bool ok = rok && (gc >= 0) && (gc < IMG);
            float4 vx = ok ? *(const float4*)(r1 + gc) : make_float4(0.f,0.f,0.f,0.f);
            float4 vy = ok ? *(const float4*)(r2 + gc) : make_float4(0.f,0.f,0.f,0.f);
            xr[4*t+0]=vx.x; xr[4*t+1]=vx.y; xr[4*t+2]=vx.z; xr[4*t+3]=vx.w;
            yr[4*t+0]=vy.x; yr[4*t+1]=vy.y; yr[4*t+2]=vy.z; yr[4*t+3]=vy.w;
        }
        float s0[4]={0,0,0,0}, s1[4]={0,0,0,0}, s2[4]={0,0,0,0},
              s3[4]={0,0,0,0}, s4[4]={0,0,0,0};
        #pragma unroll
        for (int j = 0; j < 14; ++j) {
            float x = xr[3+j], y = yr[3+j];
            float xx = x*x, yy = y*y, xy = x*y;
            #pragma unroll
            for (int o = 0; o < 4; ++o) {
                int k = j - o;
                if (0 <= k && k < 11) {
                    float w = W[k];
                    s0[o] = fmaf(w, x,  s0[o]);
                    s1[o] = fmaf(w, y,  s1[o]);
                    s2[o] = fmaf(w, xx, s2[o]);
                    s3[o] = fmaf(w, yy, s3[o]);
                    s4[o] = fmaf(w, xy, s4[o]);
                }
            }
        }
        #pragma unroll
        for (int o = 0; o < 4; ++o) {
            sH4[slot][c0+o] = make_float4(s0[o], s1[o], s2[o], s3[o]);
            sH1[slot][c0+o] = s4[o];
        }
    };

    // ---- vertical blur + SSIM for rows [r0, r0+16), 4 rows/thread with sliding window.
    auto vert = [&](int r0, int sb) {
        const int wv  = tid >> 6;       // wave id -> row group (wave-uniform)
        const int col = tid & 63;
        const int d0  = sb + (wv << 2) - HALO;
        float4 v4[14]; float v1c[14];
        #pragma unroll
        for (int i = 0; i < 14; ++i) {
            int s = d0 + i;
            s += (s < 0)     ? RING : 0;
            s -= (s >= RING) ? RING : 0;
            v4[i]  = sH4[s][col];
            v1c[i] = sH1[s][col];
        }
        #pragma unroll
        for (int q = 0; q < 4; ++q) {
            float m1=0.f, m2=0.f, e11=0.f, e22=0.f, e12=0.f;
            #pragma unroll
            for (int k = 0; k < 11; ++k) {
                float w = W[k];
                m1  = fmaf(w, v4[q+k].x, m1);
                m2  = fmaf(w, v4[q+k].y, m2);
                e11 = fmaf(w, v4[q+k].z, e11);
                e22 = fmaf(w, v4[q+k].w, e22);
                e12 = fmaf(w, v1c[q+k],  e12);
            }
            float mu1s = m1*m1, mu2s = m2*m2, mu12 = m1*m2;
            float g1 = e11 - mu1s, g2 = e22 - mu2s, g12 = e12 - mu12;
            float num = (2.0f*mu12 + C1) * (2.0f*g12 + C2);
            float den = (mu1s + mu2s + C1) * (g1 + g2 + C2);
            acc += num * __builtin_amdgcn_rcpf(den);
        }
    };

    // ---- prologue: h-blur rows base-5 .. base+20 (26 rows; OOB rows write zeros)
    for (int task = tid; task < 26 * 16; task += 256) {
        int i  = task >> 4;                       // 0..25
        int gr = base - HALO + i;
        int slot = (unsigned)(gr + RING) % (unsigned)RING;
        horiz(gr, slot, task & 15);
    }

    // ---- main loop: 16 bands, 2 barriers each
    int sb = half ? (256 % RING) : 0;             // r0 mod RING
    for (int b = 0; b < NB; ++b) {
        const int r0 = base + (b << 4);
        __syncthreads();                          // ring rows for this band ready
        vert(r0, sb);
        __syncthreads();                          // vert reads done (WAR on ring)
        if (b + 1 < NB) {
            int rr = tid >> 4;                    // 0..15
            int t  = sb + 21 + rr;
            t -= (t >= RING) ? RING : 0;
            t -= (t >= RING) ? RING : 0;
            horiz(r0 + 21 + rr, t, tid & 15);     // rows r0+21 .. r0+36
        }
        sb += BAND;
        sb -= (sb >= RING) ? RING : 0;
    }

    // ---- block reduction -> one partial per block
    #pragma unroll
    for (int off = 32; off > 0; off >>= 1)
        acc += __shfl_down(acc, off, 64);
    if ((tid & 63) == 0) sRed[tid >> 6] = acc;
    __syncthreads();
    if (tid == 0) part[bx] = sRed[0] + sRed[1] + sRed[2] + sRed[3];
}

__global__ void ssim_finalize(const float* __restrict__ part, float* __restrict__ out)
{
    double s = 0.0;
    const int t = threadIdx.x;
    for (int i = t; i < 1024; i += 64) s += (double)part[i];
    #pragma unroll
    for (int off = 32; off > 0; off >>= 1)
        s += __shfl_down(s, off, 64);
    if (t == 0) out[0] = (float)(s * (1.0 / 16777216.0));
}

extern "C" void kernel_launch(void* const* d_in, const int* in_sizes, int n_in,
                              void* d_out, int out_size, void* d_ws, size_t ws_size,
                              hipStream_t stream)
{
    const float* img1 = (const float*)d_in[0];
    const float* img2 = (const float*)d_in[1];
    float* out  = (float*)d_out;
    float* part = (float*)d_ws;      // 1024 floats of scratch

    ssim_main<<<1024, 256, 0, stream>>>(img1, img2, part);
    ssim_finalize<<<1, 64, 0, stream>>>(part, out);
}

// Round 3
// 203.873 us; speedup vs baseline: 1.3328x; 1.2970x over previous
//
#include <hip/hip_runtime.h>

#define IMG 512
#define HALO 5
#define BAND 16
#define NB 16          // bands per block (256 rows / 16)
#define RING 28        // ring slots >= 26 live rows

// Gaussian window, sigma=1.5, ws=11, normalized (matches reference _make_window)
#define W0 1.0283800e-03f
#define W1 7.5987582e-03f
#define W2 3.6000773e-02f
#define W3 1.0936070e-01f
#define W4 2.1300553e-01f
#define W5 2.6601172e-01f

typedef float f2 __attribute__((ext_vector_type(2)));

__device__ __forceinline__ f2 pkfma(f2 a, f2 b, f2 c) {
    return __builtin_elementwise_fma(a, b, c);   // -> v_pk_fma_f32
}

// Raw workgroup barrier: drain LDS only (lgkmcnt), leave global loads in flight.
// Correctness: both barriers in the band loop only order LDS ops (RAW on ring
// writes, WAR on ring reads); register-destined global prefetch needs no fence.
#define LGKM_BARRIER() asm volatile("s_waitcnt lgkmcnt(0)\n\ts_barrier" ::: "memory")

__global__ __launch_bounds__(256, 4)
void ssim_main(const float* __restrict__ img1, const float* __restrict__ img2,
               float* __restrict__ part)
{
    const float Wt[11] = {W0,W1,W2,W3,W4,W5,W4,W3,W2,W1,W0};
    constexpr float C1 = 1.0e-4f;
    constexpr float C2 = 9.0e-4f;

    // Ring of horizontal-blur results: 4 channels packed (x,y,xx,yy) + xy separate.
    __shared__ float4 sH4[RING][65];   // 29120 B
    __shared__ float  sH1[RING][65];   //  7280 B
    __shared__ float  sRed[4];         // ~36.4 KB total -> 4 blocks/CU

    const int bx     = blockIdx.x;
    const int n      = bx >> 4;                // image 0..63
    const int stripe = (bx >> 1) & 7;          // 64-col stripe
    const int half   = bx & 1;                 // row half
    const int gx0    = stripe << 6;
    const int base   = half << 8;
    const int tid    = threadIdx.x;
    const bool edge  = (stripe == 0) | (stripe == 7);

    const float* __restrict__ base1 = img1 + (size_t)n * IMG * IMG;
    const float* __restrict__ base2 = img2 + (size_t)n * IMG * IMG;

    float acc = 0.0f;

    // ---- load the 20-col window (5 aligned float4 per image) for global row gr
    auto loadRow = [&](int gr, int cg, float4* px, float4* py) {
        const int c0  = cg << 2;
        const int gcb = gx0 + c0;
        const bool rok = ((unsigned)gr < (unsigned)IMG);
        const float4* r1 = (const float4*)(base1 + (ptrdiff_t)gr * IMG + gcb - 8);
        const float4* r2 = (const float4*)(base2 + (ptrdiff_t)gr * IMG + gcb - 8);
        if (!edge && rok) {               // interior stripes: no col predication
            #pragma unroll
            for (int t = 0; t < 5; ++t) { px[t] = r1[t]; py[t] = r2[t]; }
        } else {
            #pragma unroll
            for (int t = 0; t < 5; ++t) {
                int gc = gcb - 8 + (t << 2);
                bool ok = rok && (gc >= 0) && (gc < IMG);
                px[t] = ok ? r1[t] : make_float4(0.f,0.f,0.f,0.f);
                py[t] = ok ? r2[t] : make_float4(0.f,0.f,0.f,0.f);
            }
        }
    };

    // ---- horizontal blur (packed f32) of a preloaded row -> ring[slot], 4 cols
    auto horizStore = [&](const float4* px, const float4* py, int slot, int cg) {
        const int c0 = cg << 2;
        float X[20], Y[20];
        #pragma unroll
        for (int t = 0; t < 5; ++t) {
            X[4*t+0]=px[t].x; X[4*t+1]=px[t].y; X[4*t+2]=px[t].z; X[4*t+3]=px[t].w;
            Y[4*t+0]=py[t].x; Y[4*t+1]=py[t].y; Y[4*t+2]=py[t].z; Y[4*t+3]=py[t].w;
        }
        f2 s01[4] = {{0,0},{0,0},{0,0},{0,0}};
        f2 s23[4] = {{0,0},{0,0},{0,0},{0,0}};
        float s4[4] = {0,0,0,0};
        #pragma unroll
        for (int j = 3; j <= 16; ++j) {
            f2 pxy = {X[j], Y[j]};
            f2 psq = pxy * pxy;           // (x^2, y^2) via v_pk_mul_f32
            float sxy = X[j] * Y[j];
            #pragma unroll
            for (int o = 0; o < 4; ++o) {
                int k = j - 3 - o;
                if (0 <= k && k < 11) {
                    f2 w2 = {Wt[k], Wt[k]};
                    s01[o] = pkfma(w2, pxy, s01[o]);
                    s23[o] = pkfma(w2, psq, s23[o]);
                    s4[o]  = fmaf(Wt[k], sxy, s4[o]);
                }
            }
        }
        #pragma unroll
        for (int o = 0; o < 4; ++o) {
            sH4[slot][c0+o] = make_float4(s01[o].x, s01[o].y, s23[o].x, s23[o].y);
            sH1[slot][c0+o] = s4[o];
        }
    };

    // ---- vertical blur + SSIM for 16 rows (4 rows/thread, sliding window)
    auto vert = [&](int sb) {
        const int wv  = tid >> 6;
        const int col = tid & 63;
        const int d0  = sb + (wv << 2) - HALO;
        f2 a[14], b[14]; float c[14];
        #pragma unroll
        for (int i = 0; i < 14; ++i) {
            int s = d0 + i;
            s += (s < 0)     ? RING : 0;
            s -= (s >= RING) ? RING : 0;
            float4 t4 = sH4[s][col];
            a[i] = f2{t4.x, t4.y};
            b[i] = f2{t4.z, t4.w};
            c[i] = sH1[s][col];
        }
        #pragma unroll
        for (int q = 0; q < 4; ++q) {
            f2 m = {0,0}, e = {0,0}; float e12 = 0.f;
            #pragma unroll
            for (int k = 0; k < 11; ++k) {
                f2 w2 = {Wt[k], Wt[k]};
                m   = pkfma(w2, a[q+k], m);
                e   = pkfma(w2, b[q+k], e);
                e12 = fmaf(Wt[k], c[q+k], e12);
            }
            f2 msq = m * m;                    // (mu1^2, mu2^2)
            float mu12 = m.x * m.y;
            f2 g = e - msq;                    // (sigma1^2, sigma2^2)
            float g12 = e12 - mu12;
            float num = (2.0f*mu12 + C1) * (2.0f*g12 + C2);
            float den = (msq.x + msq.y + C1) * (g.x + g.y + C2);
            acc += num * __builtin_amdgcn_rcpf(den);
        }
    };

    // ---- prologue: h-blur rows base-5 .. base+20 (26 rows)
    for (int task = tid; task < 26 * 16; task += 256) {
        int i  = task >> 4;
        int cg = task & 15;
        int gr = base - HALO + i;
        int slot = (unsigned)(gr + 2*RING) % (unsigned)RING;
        float4 px[5], py[5];
        loadRow(gr, cg, px, py);
        horizStore(px, py, slot, cg);
    }

    // ---- main loop: prefetch -> barrier -> vert -> barrier -> horiz
    int sb = half ? (256 % RING) : 0;
    const int rr = tid >> 4, cg = tid & 15;
    for (int b = 0; b < NB; ++b) {
        float4 px[5], py[5];
        const bool pf = (b + 1 < NB);
        if (pf) loadRow(base + (b << 4) + 21 + rr, cg, px, py);  // in flight across vert
        LGKM_BARRIER();                        // ring rows for this band ready
        vert(sb);
        LGKM_BARRIER();                        // vert reads done (WAR on ring)
        if (pf) {
            int t = sb + 21 + rr;
            t -= (t >= RING) ? RING : 0;
            t -= (t >= RING) ? RING : 0;
            horizStore(px, py, t, cg);
        }
        sb += BAND;
        sb -= (sb >= RING) ? RING : 0;
    }

    // ---- block reduction -> one partial per block
    #pragma unroll
    for (int off = 32; off > 0; off >>= 1)
        acc += __shfl_down(acc, off, 64);
    if ((tid & 63) == 0) sRed[tid >> 6] = acc;
    LGKM_BARRIER();
    if (tid == 0) part[bx] = sRed[0] + sRed[1] + sRed[2] + sRed[3];
}

__global__ void ssim_finalize(const float* __restrict__ part, float* __restrict__ out)
{
    double s = 0.0;
    const int t = threadIdx.x;
    for (int i = t; i < 1024; i += 64) s += (double)part[i];
    #pragma unroll
    for (int off = 32; off > 0; off >>= 1)
        s += __shfl_down(s, off, 64);
    if (t == 0) out[0] = (float)(s * (1.0 / 16777216.0));
}

extern "C" void kernel_launch(void* const* d_in, const int* in_sizes, int n_in,
                              void* d_out, int out_size, void* d_ws, size_t ws_size,
                              hipStream_t stream)
{
    const float* img1 = (const float*)d_in[0];
    const float* img2 = (const float*)d_in[1];
    float* out  = (float*)d_out;
    float* part = (float*)d_ws;      // 1024 floats of scratch

    ssim_main<<<1024, 256, 0, stream>>>(img1, img2, part);
    ssim_finalize<<<1, 64, 0, stream>>>(part, out);
}

// Round 4
// 174.582 us; speedup vs baseline: 1.5564x; 1.1678x over previous
//
#include <hip/hip_runtime.h>

#define IMG 512
#define HALO 5
#define BAND 16
#define NB 16          // bands per block (256 rows / 16)
#define RING 28        // ring slots >= 26 live rows

// Gaussian window, sigma=1.5, ws=11, normalized (matches reference _make_window)
#define W0 1.0283800e-03f
#define W1 7.5987582e-03f
#define W2 3.6000773e-02f
#define W3 1.0936070e-01f
#define W4 2.1300553e-01f
#define W5 2.6601172e-01f

typedef float f2 __attribute__((ext_vector_type(2)));

__device__ __forceinline__ f2 pkfma(f2 a, f2 b, f2 c) {
    return __builtin_elementwise_fma(a, b, c);   // -> v_pk_fma_f32
}

// Raw workgroup barrier: drain LDS only, leave global loads in flight.
#define LGKM_BARRIER() asm volatile("s_waitcnt lgkmcnt(0)\n\ts_barrier" ::: "memory")

__global__ __launch_bounds__(256, 4)
void ssim_main(const float* __restrict__ img1, const float* __restrict__ img2,
               float* __restrict__ part)
{
    const float Wt[11] = {W0,W1,W2,W3,W4,W5,W4,W3,W2,W1,W0};
    constexpr float C1 = 1.0e-4f;
    constexpr float C2 = 9.0e-4f;

    // Ring of horizontal-blur results, 4 fused channels per px:
    //   (bx = h-blur(x), by = h-blur(y), bs = h-blur(x^2+y^2), bp = h-blur(x*y))
    // sigma1_sq+sigma2_sq = blur(x^2+y^2) - mu1^2 - mu2^2 (blur is linear).
    // Slot of image row gr is (gr - base + 5) mod RING.
    __shared__ float4 sH[RING][65];    // 29120 B -> 5 blocks/CU capacity
    __shared__ float  sRed[4];

    const int bx     = blockIdx.x;
    const int n      = bx >> 4;                // image 0..63
    const int stripe = (bx >> 1) & 7;          // 64-col stripe
    const int half   = bx & 1;                 // row half
    const int gx0    = stripe << 6;
    const int base   = half << 8;
    const int tid    = threadIdx.x;
    const bool edge  = (stripe == 0) | (stripe == 7);

    const float* __restrict__ base1 = img1 + (size_t)n * IMG * IMG;
    const float* __restrict__ base2 = img2 + (size_t)n * IMG * IMG;

    float acc = 0.0f;

    // ---- predicated 20-col window load (5 aligned float4 per image)
    auto loadRowP = [&](const float* r1, const float* r2, bool rok, int gcb,
                        float4* px, float4* py) {
        #pragma unroll
        for (int t = 0; t < 5; ++t) {
            int gc = gcb - 8 + (t << 2);
            bool ok = rok && (gc >= 0) && (gc < IMG);
            px[t] = ok ? ((const float4*)r1)[t] : make_float4(0.f,0.f,0.f,0.f);
            py[t] = ok ? ((const float4*)r2)[t] : make_float4(0.f,0.f,0.f,0.f);
        }
    };

    // ---- horizontal blur of a preloaded row -> ring[slot], 4 output cols
    auto horizStore = [&](const float4* px, const float4* py, int slot, int cg) {
        const int c0 = cg << 2;
        float X[20], Y[20];
        #pragma unroll
        for (int t = 0; t < 5; ++t) {
            X[4*t+0]=px[t].x; X[4*t+1]=px[t].y; X[4*t+2]=px[t].z; X[4*t+3]=px[t].w;
            Y[4*t+0]=py[t].x; Y[4*t+1]=py[t].y; Y[4*t+2]=py[t].z; Y[4*t+3]=py[t].w;
        }
        f2 xy[14], sp[14];
        #pragma unroll
        for (int j = 0; j < 14; ++j) {
            float x = X[3+j], y = Y[3+j];
            xy[j] = f2{x, y};
            sp[j] = f2{fmaf(x, x, y*y), x*y};
        }
        #pragma unroll
        for (int o = 0; o < 4; ++o) {
            f2 m = {0.f, 0.f}, t2 = {0.f, 0.f};
            #pragma unroll
            for (int k = 0; k < 11; ++k) {
                f2 w2 = {Wt[k], Wt[k]};
                m  = pkfma(w2, xy[o+k], m);
                t2 = pkfma(w2, sp[o+k], t2);
            }
            sH[slot][c0+o] = make_float4(m.x, m.y, t2.x, t2.y);
        }
    };

    // ---- prologue: h-blur rows base-5 .. base+20 into slots 0..25 (no mod)
    for (int task = tid; task < 26 * 16; task += 256) {
        int i   = task >> 4;                   // 0..25 == slot
        int cg  = task & 15;
        int gr  = base - HALO + i;
        int gcb = gx0 + (cg << 2);
        const float* r1 = base1 + (ptrdiff_t)gr * IMG + gcb - 8;
        const float* r2 = base2 + (ptrdiff_t)gr * IMG + gcb - 8;
        float4 px[5], py[5];
        loadRowP(r1, r2, (unsigned)gr < (unsigned)IMG, gcb, px, py);
        horizStore(px, py, i, cg);
    }

    // ---- steady-state pointers: this thread's prefetch row for band b is
    //      base + 16b + 21 + rr at cols gcb-8 .. gcb+11
    const int rr  = tid >> 4;                  // 0..15
    const int cgs = tid & 15;
    const int gcb = gx0 + (cgs << 2);
    const float* p1 = base1 + (ptrdiff_t)(base + 21 + rr) * IMG + gcb - 8;
    const float* p2 = base2 + (ptrdiff_t)(base + 21 + rr) * IMG + gcb - 8;

    int sb = 0;                                // (16*b) mod RING, scalar
    for (int b = 0; b < NB; ++b) {
        float4 px[5], py[5];
        const bool pf = (b + 1 < NB);
        if (pf) {
            // rows OOB only possible when half==1 && b==14 (rows 501..516)
            const bool rowsafe = (half == 0) | (b < 14);
            if (rowsafe & (!edge)) {
                #pragma unroll
                for (int t = 0; t < 5; ++t) {
                    px[t] = ((const float4*)p1)[t];
                    py[t] = ((const float4*)p2)[t];
                }
            } else {
                int gr = base + (b << 4) + 21 + rr;
                loadRowP(p1, p2, (unsigned)gr < (unsigned)IMG, gcb, px, py);
            }
        }

        LGKM_BARRIER();                        // ring rows for this band ready

        // ---- vertical blur + SSIM: 4 rows/thread, wave-uniform slot math
        {
            const int wv  = __builtin_amdgcn_readfirstlane(tid >> 6);
            const int col = tid & 63;
            const int d0  = sb + (wv << 2);    // uniform, <= 39
            f2 a[14], p[14];
            #pragma unroll
            for (int i = 0; i < 14; ++i) {
                int s = d0 + i;
                s -= (s >= RING) ? RING : 0;
                s -= (s >= RING) ? RING : 0;
                float4 q = sH[s][col];
                a[i] = f2{q.x, q.y};           // (bx, by) — adjacent halves
                p[i] = f2{q.z, q.w};           // (bs, bp)
            }
            #pragma unroll
            for (int q4 = 0; q4 < 4; ++q4) {
                f2 m = {0.f,0.f}, tt = {0.f,0.f};
                #pragma unroll
                for (int k = 0; k < 11; ++k) {
                    f2 w2 = {Wt[k], Wt[k]};
                    m  = pkfma(w2, a[q4+k], m);
                    tt = pkfma(w2, p[q4+k], tt);
                }
                f2 msq     = m * m;            // (mu1^2, mu2^2)
                float mu12  = m.x * m.y;
                float musum = msq.x + msq.y;
                float g12   = tt.y - mu12;     // sigma12
                float gs    = tt.x - musum;    // sigma1^2 + sigma2^2
                float num = fmaf(2.f, mu12, C1) * fmaf(2.f, g12, C2);
                float den = (musum + C1) * (gs + C2);
                acc = fmaf(num, __builtin_amdgcn_rcpf(den), acc);
            }
        }

        LGKM_BARRIER();                        // vert reads done (WAR on ring)

        if (pf) {
            int t = sb + 26 + rr;              // slot of row base+16b+21+rr
            t -= (t >= RING) ? RING : 0;
            t -= (t >= RING) ? RING : 0;
            horizStore(px, py, t, cgs);
            p1 += BAND * IMG;
            p2 += BAND * IMG;
        }
        sb += BAND;
        sb -= (sb >= RING) ? RING : 0;
    }

    // ---- block reduction -> one partial per block
    #pragma unroll
    for (int off = 32; off > 0; off >>= 1)
        acc += __shfl_down(acc, off, 64);
    if ((tid & 63) == 0) sRed[tid >> 6] = acc;
    LGKM_BARRIER();
    if (tid == 0) part[bx] = sRed[0] + sRed[1] + sRed[2] + sRed[3];
}

__global__ void ssim_finalize(const float* __restrict__ part, float* __restrict__ out)
{
    double s = 0.0;
    const int t = threadIdx.x;
    for (int i = t; i < 1024; i += 64) s += (double)part[i];
    #pragma unroll
    for (int off = 32; off > 0; off >>= 1)
        s += __shfl_down(s, off, 64);
    if (t == 0) out[0] = (float)(s * (1.0 / 16777216.0));
}

extern "C" void kernel_launch(void* const* d_in, const int* in_sizes, int n_in,
                              void* d_out, int out_size, void* d_ws, size_t ws_size,
                              hipStream_t stream)
{
    const float* img1 = (const float*)d_in[0];
    const float* img2 = (const float*)d_in[1];
    float* out  = (float*)d_out;
    float* part = (float*)d_ws;      // 1024 floats of scratch

    ssim_main<<<1024, 256, 0, stream>>>(img1, img2, part);
    ssim_finalize<<<1, 64, 0, stream>>>(part, out);
}